// Round 15
// baseline (656.802 us; speedup 1.0000x reference)
//
#include <hip/hip_runtime.h>
#include <hip/hip_bf16.h>
#include <cstdint>
#include <cstddef>

// ---------------- problem constants ----------------
#define B_    8
#define S_    1500
#define D_    1024
#define H_    16
#define HD_   64
#define DFF_  4096
#define M_    12000   // B_*S_
#define VTS_  1536    // padded seq stride for V^T

typedef __bf16 bf16;
typedef __attribute__((ext_vector_type(8))) __bf16 bf16x8;
typedef __attribute__((ext_vector_type(4))) float f32x4;

#define MFMA16(a, b, c) __builtin_amdgcn_mfma_f32_16x16x32_bf16((a), (b), (c), 0, 0, 0)

// async global->LDS, 16B per lane (wave-uniform base + lane*16 dest).
static __device__ __forceinline__ void gload16(const void* g, void* l) {
  __builtin_amdgcn_global_load_lds(
      (const __attribute__((address_space(1))) void*)(uintptr_t)g,
      (__attribute__((address_space(3))) void*)(uintptr_t)l, 16, 0, 0);
}

static __device__ __forceinline__ unsigned short f2bu(float v) {
  bf16 h = (bf16)v;
  union { bf16 h; unsigned short u; } c;
  c.h = h;
  return c.u;
}

// ---------------- workspace layout (bytes) ----------------
static constexpr size_t HSZ      = (size_t)M_ * D_ * 2;             // 24,576,000
static constexpr size_t H_OFF    = 0;
static constexpr size_t WQ_OFF   = H_OFF + HSZ;                     // 24,576,000
static constexpr size_t WK_OFF   = WQ_OFF + (size_t)D_ * D_ * 2;
static constexpr size_t WV_OFF   = WK_OFF + (size_t)D_ * D_ * 2;
static constexpr size_t WO_OFF   = WV_OFF + (size_t)D_ * D_ * 2;
static constexpr size_t Q_OFF    = WO_OFF + (size_t)D_ * D_ * 2;    // 32,964,608
static constexpr size_t K_OFF    = Q_OFF + HSZ;                     // 57,540,608
static constexpr size_t VT_OFF   = K_OFF + HSZ;                     // 82,116,608
static constexpr size_t W1_OFF   = VT_OFF + (size_t)128 * 64 * VTS_ * 2;  // 107,282,432
static constexpr size_t W2_OFF   = W1_OFF + (size_t)DFF_ * D_ * 2;  // 115,671,040
static constexpr size_t WS_BASE  = W2_OFF + (size_t)DFF_ * D_ * 2;  // 124,059,648
static constexpr size_t H2B_OFF  = WS_BASE;                         // big path h2
static constexpr size_t NEED_BIG = WS_BASE + HSZ;                   // 148,635,648
static constexpr size_t H2F_OFF  = VT_OFF;                          // fallback h2
static constexpr size_t ACT_OFF  = 0;                               // both paths

// ---------------- fp32 -> bf16 convert ----------------
__launch_bounds__(256)
__global__ void cvt_bf16(const float* __restrict__ src, bf16* __restrict__ dst, int n) {
  int i = (blockIdx.x * 256 + threadIdx.x) * 4;
  if (i < n) {
    float4 f = *(const float4*)(src + i);
    dst[i + 0] = (bf16)f.x;
    dst[i + 1] = (bf16)f.y;
    dst[i + 2] = (bf16)f.z;
    dst[i + 3] = (bf16)f.w;
  }
}

// ---------------- fused LayerNorm (fp32 in, bf16 out), one block per row ----------------
__launch_bounds__(256)
__global__ void ln_fused(const float* __restrict__ x, const float* __restrict__ g,
                         const float* __restrict__ bb, bf16* __restrict__ out) {
  const int row = blockIdx.x;
  const int t = threadIdx.x;
  const float4 xv = *(const float4*)(x + (size_t)row * D_ + t * 4);
  float s  = xv.x + xv.y + xv.z + xv.w;
  float s2 = xv.x * xv.x + xv.y * xv.y + xv.z * xv.z + xv.w * xv.w;
#pragma unroll
  for (int m = 32; m >= 1; m >>= 1) {
    s  += __shfl_xor(s, m);
    s2 += __shfl_xor(s2, m);
  }
  __shared__ float red[8];
  const int w = t >> 6;
  if ((t & 63) == 0) { red[w] = s; red[4 + w] = s2; }
  __syncthreads();
  s  = red[0] + red[1] + red[2] + red[3];
  s2 = red[4] + red[5] + red[6] + red[7];
  const float mu  = s * (1.0f / D_);
  const float var = s2 * (1.0f / D_) - mu * mu;
  const float rs  = rsqrtf(var + 1e-5f);
  const float4 gv = *(const float4*)(g + t * 4);
  const float4 bv = *(const float4*)(bb + t * 4);
  bf16* o = out + (size_t)row * D_ + t * 4;
  o[0] = (bf16)((xv.x - mu) * rs * gv.x + bv.x);
  o[1] = (bf16)((xv.y - mu) * rs * gv.y + bv.y);
  o[2] = (bf16)((xv.z - mu) * rs * gv.z + bv.z);
  o[3] = (bf16)((xv.w - mu) * rs * gv.w + bv.w);
}

// =====================================================================================
// gemm256 v6 (r14): 16 waves, 64x64/wave, BK=64, 2 LDS buffers, XCD-chunk swizzle.
// EPI: 2 = bias + exact GELU -> bf16; 3 = (+bias) + resid -> fp32 (resid may alias outF);
//      5 = fused QKV epilogue (Q pre-scaled by 0.125*log2e for exp2-domain softmax)
// =====================================================================================
template <int EPI>
__launch_bounds__(1024, 4)
__global__ void gemm256(const bf16* __restrict__ A, const bf16* __restrict__ Bw,
                        int M, int N, int K, int nbx, int nby,
                        bf16* __restrict__ outB, float* outF,
                        const float* __restrict__ bias, const float* resid,
                        bf16* __restrict__ outQ, bf16* __restrict__ outK2,
                        bf16* __restrict__ outV) {
  __shared__ bf16 a_lds[2][256 * 64];
  __shared__ bf16 b_lds[2][256 * 64];

  // bijective XCD-chunk remap (m204)
  const int nwg = nbx * nby;
  const int lid = blockIdx.x;
  const int xcd = lid & 7;
  const int q8 = nwg >> 3, r8 = nwg & 7;
  const int wgid = (xcd < r8 ? xcd * (q8 + 1) : r8 * (q8 + 1) + (xcd - r8) * q8) + (lid >> 3);
  const int bx = wgid / nby;
  const int by = wgid - bx * nby;

  const int t = threadIdx.x;
  const int lane = t & 63, wid = t >> 6;
  const int wm = wid >> 2, wn = wid & 3;
  const int l15 = lane & 15, hi = lane >> 4;
  const int l7 = l15 & 7;
  const int mrow0 = bx * 256;
  const int ncol0 = by * 256;

  const int rl = t >> 3;
  const int sc8 = ((t & 7) ^ (rl & 7)) << 3;
  unsigned offA[2], offB[2];
#pragma unroll
  for (int j = 0; j < 2; ++j) {
    int gr = mrow0 + j * 128 + rl; gr = gr < M ? gr : M - 1;
    offA[j] = (unsigned)gr * (unsigned)K + (unsigned)sc8;
    offB[j] = (unsigned)(ncol0 + j * 128 + rl) * (unsigned)K + (unsigned)sc8;
  }

  f32x4 acc[4][4] = {};

  const int NT = K >> 6;

  {
    char* ad = (char*)&a_lds[0][0];
    char* bd = (char*)&b_lds[0][0];
    gload16(A + offA[0], ad + t * 16);
    gload16(A + offA[1], ad + 16384 + t * 16);
    gload16(Bw + offB[0], bd + t * 16);
    gload16(Bw + offB[1], bd + 16384 + t * 16);
  }
  __syncthreads();

  int buf = 0;
  for (int tt = 0; tt < NT; ++tt) {
    if (tt + 1 < NT) {
      const unsigned k1 = (unsigned)(tt + 1) << 6;
      char* ad = (char*)&a_lds[buf ^ 1][0];
      char* bd = (char*)&b_lds[buf ^ 1][0];
      gload16(A + offA[0] + k1, ad + t * 16);
      gload16(A + offA[1] + k1, ad + 16384 + t * 16);
      gload16(Bw + offB[0] + k1, bd + t * 16);
      gload16(Bw + offB[1] + k1, bd + 16384 + t * 16);
    }

    const bf16* al = &a_lds[buf][0];
    const bf16* bl = &b_lds[buf][0];
#pragma unroll
    for (int kk = 0; kk < 2; ++kk) {
      bf16x8 af_[4], bf_[4];
      const int cc = ((kk * 4 + hi) ^ l7) << 3;
#pragma unroll
      for (int m = 0; m < 4; ++m)
        af_[m] = *(const bf16x8*)&al[(wm * 64 + m * 16 + l15) * 64 + cc];
#pragma unroll
      for (int n = 0; n < 4; ++n)
        bf_[n] = *(const bf16x8*)&bl[(wn * 64 + n * 16 + l15) * 64 + cc];
      __builtin_amdgcn_s_setprio(1);
#pragma unroll
      for (int m = 0; m < 4; ++m)
#pragma unroll
        for (int n = 0; n < 4; ++n)
          acc[m][n] = MFMA16(af_[m], bf_[n], acc[m][n]);
      __builtin_amdgcn_s_setprio(0);
    }

    __syncthreads();
    buf ^= 1;
  }

  const int r0 = hi * 4;

  if constexpr (EPI == 5) {
    const int mm = by >> 2;
    const int nloc0 = (by & 3) * 256;
    if (mm == 2) {
#pragma unroll
      for (int m = 0; m < 4; ++m) {
        int row0 = mrow0 + wm * 64 + m * 16 + r0;
        if (row0 < M) {
          int bb2 = row0 / 1500;
          int s = row0 - bb2 * 1500;
#pragma unroll
          for (int n = 0; n < 4; ++n) {
            int f = nloc0 + wn * 64 + n * 16 + l15;
            size_t a = ((size_t)(bb2 * 16 + (f >> 6)) * 64 + (f & 63)) * VTS_ + s;
            ushort4 pk;
            pk.x = f2bu(acc[m][n][0]);
            pk.y = f2bu(acc[m][n][1]);
            pk.z = f2bu(acc[m][n][2]);
            pk.w = f2bu(acc[m][n][3]);
            *reinterpret_cast<ushort4*>((unsigned short*)outV + a) = pk;
          }
        }
      }
    } else {
      bf16* dst = (mm == 0) ? outQ : outK2;
      const float sc = (mm == 0) ? 0.18033688011112042f : 1.0f;
#pragma unroll
      for (int m = 0; m < 4; ++m) {
#pragma unroll
        for (int n = 0; n < 4; ++n) {
          int col = nloc0 + wn * 64 + n * 16 + l15;
#pragma unroll
          for (int r = 0; r < 4; ++r) {
            int row = mrow0 + wm * 64 + m * 16 + r0 + r;
            if (row < M) dst[(size_t)row * D_ + col] = (bf16)(acc[m][n][r] * sc);
          }
        }
      }
    }
    return;
  }

#pragma unroll
  for (int m = 0; m < 4; ++m) {
#pragma unroll
    for (int n = 0; n < 4; ++n) {
      int col = ncol0 + wn * 64 + n * 16 + l15;
#pragma unroll
      for (int r = 0; r < 4; ++r) {
        int row = mrow0 + wm * 64 + m * 16 + r0 + r;
        if (row < M) {
          float v = acc[m][n][r];
          if constexpr (EPI == 2) {
            float xg = v + bias[col];
            v = 0.5f * xg * (1.0f + erff(xg * 0.70710678118654752f));
            outB[(size_t)row * N + col] = (bf16)v;
          }
          if constexpr (EPI == 3) {
            v += resid[(size_t)row * N + col];
            if (bias) v += bias[col];
            outF[(size_t)row * N + col] = v;
          }
        }
      }
    }
  }
}

// ---------------- legacy 128x128 GEMM (fallback FFN2 only) ----------------
template <int EPI>
__launch_bounds__(256)
__global__ void gemm_bt(const bf16* __restrict__ A, const bf16* __restrict__ Bw,
                        int M, int N, int K,
                        bf16* __restrict__ outB, float* outF,
                        const float* __restrict__ bias, const float* resid,
                        float scale) {
  __shared__ bf16 a_lds[128 * 64];
  __shared__ bf16 b_lds[128 * 64];
  const int t = threadIdx.x;
  const int lane = t & 63, wid = t >> 6;
  const int wr = wid >> 1, wc = wid & 1;
  const int mrow0 = blockIdx.x * 128;
  const int ncol0 = blockIdx.y * 128;
  const int l15 = lane & 15;
  const int khi = (lane >> 4) << 3;

  f32x4 acc[4][4] = {};

  for (int k0 = 0; k0 < K; k0 += 64) {
#pragma unroll
    for (int i = 0; i < 4; ++i) {
      int idx = i * 2048 + t * 8;
      int row = idx >> 6, col = idx & 63;
      int gr = mrow0 + row;
      gr = gr < M ? gr : M - 1;
      gload16(A + (size_t)gr * K + (k0 + col), (char*)a_lds + idx * 2);
    }
#pragma unroll
    for (int i = 0; i < 4; ++i) {
      int idx = i * 2048 + t * 8;
      int row = idx >> 6, col = idx & 63;
      gload16(Bw + (size_t)(ncol0 + row) * K + (k0 + col), (char*)b_lds + idx * 2);
    }
    __syncthreads();
#pragma unroll
    for (int kk = 0; kk < 2; ++kk) {
      bf16x8 af[4], bfv[4];
#pragma unroll
      for (int m = 0; m < 4; ++m)
        af[m] = *(const bf16x8*)&a_lds[(wr * 64 + m * 16 + l15) * 64 + kk * 32 + khi];
#pragma unroll
      for (int n = 0; n < 4; ++n)
        bfv[n] = *(const bf16x8*)&b_lds[(wc * 64 + n * 16 + l15) * 64 + kk * 32 + khi];
#pragma unroll
      for (int m = 0; m < 4; ++m)
#pragma unroll
        for (int n = 0; n < 4; ++n)
          acc[m][n] = MFMA16(af[m], bfv[n], acc[m][n]);
    }
    __syncthreads();
  }

  const int r0 = (lane >> 4) << 2;
#pragma unroll
  for (int m = 0; m < 4; ++m) {
#pragma unroll
    for (int n = 0; n < 4; ++n) {
      int col = ncol0 + wc * 64 + n * 16 + l15;
#pragma unroll
      for (int r = 0; r < 4; ++r) {
        int row = mrow0 + wr * 64 + m * 16 + r0 + r;
        if (row < M) {
          float v = acc[m][n][r];
          if constexpr (EPI == 2) {
            float xg = v + bias[col];
            v = 0.5f * xg * (1.0f + erff(xg * 0.70710678118654752f));
          }
          if constexpr (EPI == 3) {
            v += resid[(size_t)row * N + col];
            if (bias) v += bias[col];
            outF[(size_t)row * N + col] = v;
          } else {
            outB[(size_t)row * N + col] = (bf16)v;
          }
        }
      }
    }
  }
}

// ---------------- flash attention fwd v8: single-buffered K/V, 6 blocks/CU ----------------
// LDS = 8K(K) + 8K(V) + 8K(P) = 24576 B -> 6 blocks/CU (24 waves, 75% cap) vs v6's 4.
// 3 barriers/tile: (a) staged K,V visible; (b) k_lds free -> stage K(kt+1) overlapping
// softmax+P+PV; (c) v_lds free -> stage V(kt+1) (exposed per block, hidden by 6-way TLP).
// p_lds per-wave (DS wave-ordered, no cross-wave hazard). Softmax identical to v6.
__launch_bounds__(256, 6)
__global__ void attn_fwd8(const bf16* __restrict__ q, const bf16* __restrict__ kg,
                          const bf16* __restrict__ vt, bf16* __restrict__ cx) {
  __shared__ bf16 k_lds[64 * 64];
  __shared__ bf16 v_lds[64 * 64];
  __shared__ bf16 p_lds[4][16 * 64];   // stride 64, XOR chunk swizzle (0 conflicts)

  const int t = threadIdx.x;
  const int lane = t & 63, w = t >> 6;
  const int L = blockIdx.x;
  const int wu = (L & 7) * 384 + (L >> 3);   // XCD head-grouping
  const int bh = wu / 24;
  const int qt = wu - bh * 24;
  const int l15 = lane & 15;
  const int hi = lane >> 4;
  const int khi = hi << 3;

  const size_t hoff = ((size_t)(bh >> 4) * S_) * D_ + (size_t)(bh & 15) * HD_;
  const bf16* qh = q + hoff;
  const bf16* kh = kg + hoff;
  const bf16* vh = vt + (size_t)bh * (64 * VTS_);

  const int st_r0 = t >> 3;
  const int st_c  = t & 7;

  int qr = qt * 64 + w * 16 + l15;
  int qrc = qr < S_ ? qr : S_ - 1;
  const bf16x8 qf0 = *(const bf16x8*)(qh + (size_t)qrc * D_ + khi);
  const bf16x8 qf1 = *(const bf16x8*)(qh + (size_t)qrc * D_ + 32 + khi);

  f32x4 oacc[4] = {};
  float mrun[4], lrun[4];
#pragma unroll
  for (int r = 0; r < 4; ++r) { mrun[r] = -1e30f; lrun[r] = 0.f; }

  bf16* pw = &p_lds[w][0];
  const int NT = (S_ + 63) / 64;  // 24
  const float THR = 11.5415605f;  // 8 nats in log2 domain

  // prologue: stage tile 0
#pragma unroll
  for (int i = 0; i < 2; ++i) {
    int row = i * 32 + st_r0;
    int sc = st_c ^ (row & 7);
    int key = row < S_ ? row : S_ - 1;
    gload16(kh + (size_t)key * D_ + sc * 8, (char*)&k_lds[0] + (i * 2048 + t * 8) * 2);
    gload16(vh + (size_t)row * VTS_ + sc * 8, (char*)&v_lds[0] + (i * 2048 + t * 8) * 2);
  }

  for (int kt = 0; kt < NT; ++kt) {
    __syncthreads();   // (a) staged K,V for kt visible (drains each wave's gloads)

    // ---- S2 = Q K^T from swizzled k_lds ----
    float pv[4][4];
    __builtin_amdgcn_s_setprio(1);
#pragma unroll
    for (int nb = 0; nb < 4; ++nb) {
      int krow = nb * 16 + l15;
      f32x4 z = {};
      z = MFMA16(qf0, *(const bf16x8*)&k_lds[krow * 64 + ((hi ^ (l15 & 7)) << 3)], z);
      z = MFMA16(qf1, *(const bf16x8*)&k_lds[krow * 64 + (((4 + hi) ^ (l15 & 7)) << 3)], z);
#pragma unroll
      for (int r = 0; r < 4; ++r) pv[nb][r] = z[r];
    }
    __builtin_amdgcn_s_setprio(0);

    __syncthreads();   // (b) all waves done reading k_lds

    // stage K(kt+1) now; lands while softmax+PV run
    if (kt + 1 < NT) {
      int kb = (kt + 1) * 64;
#pragma unroll
      for (int i = 0; i < 2; ++i) {
        int row = i * 32 + st_r0;
        int sc = st_c ^ (row & 7);
        int key = kb + row;
        key = key < S_ ? key : S_ - 1;
        gload16(kh + (size_t)key * D_ + sc * 8,
                (char*)&k_lds[0] + (i * 2048 + t * 8) * 2);
      }
    }

    if (kt == NT - 1) {
#pragma unroll
      for (int nb = 0; nb < 4; ++nb) {
        bool cvld = (kt * 64 + nb * 16 + l15) < S_;
#pragma unroll
        for (int r = 0; r < 4; ++r) pv[nb][r] = cvld ? pv[nb][r] : -1e30f;
      }
    }

    float lmax[4];
    bool ok = true;
#pragma unroll
    for (int r = 0; r < 4; ++r) {
      lmax[r] = fmaxf(fmaxf(pv[0][r], pv[1][r]), fmaxf(pv[2][r], pv[3][r]));
      ok = ok && (lmax[r] <= mrun[r] + THR);
    }
    if (!__all(ok)) {
#pragma unroll
      for (int r = 0; r < 4; ++r) {
        float mx = lmax[r];
        mx = fmaxf(mx, __shfl_xor(mx, 1));
        mx = fmaxf(mx, __shfl_xor(mx, 2));
        mx = fmaxf(mx, __shfl_xor(mx, 4));
        mx = fmaxf(mx, __shfl_xor(mx, 8));
        float mnew = fmaxf(mrun[r], mx);
        float corr = exp2f(mrun[r] - mnew);
        lrun[r] *= corr;
        mrun[r] = mnew;
#pragma unroll
        for (int db = 0; db < 4; ++db) oacc[db][r] *= corr;
      }
    }

#pragma unroll
    for (int r = 0; r < 4; ++r) {
      float p0 = exp2f(pv[0][r] - mrun[r]);
      float p1 = exp2f(pv[1][r] - mrun[r]);
      float p2 = exp2f(pv[2][r] - mrun[r]);
      float p3 = exp2f(pv[3][r] - mrun[r]);
      pv[0][r] = p0; pv[1][r] = p1; pv[2][r] = p2; pv[3][r] = p3;
      lrun[r] += (p0 + p1) + (p2 + p3);
    }

#pragma unroll
    for (int nb = 0; nb < 4; ++nb) {
#pragma unroll
      for (int r = 0; r < 4; ++r) {
        int prow = hi * 4 + r;
        int pcol = (nb * 16 + l15) ^ ((prow & 7) << 3);
        pw[prow * 64 + pcol] = (bf16)pv[nb][r];
      }
    }

    // ---- ctx += P @ V from swizzled v_lds ----
    __builtin_amdgcn_s_setprio(1);
#pragma unroll
    for (int kk = 0; kk < 2; ++kk) {
      bf16x8 pf = *(const bf16x8*)&pw[l15 * 64 + (((kk * 4 + hi) ^ (l15 & 7)) << 3)];
#pragma unroll
      for (int db = 0; db < 4; ++db) {
        int vrow = db * 16 + l15;
        bf16x8 vf = *(const bf16x8*)&v_lds[vrow * 64 + (((kk * 4 + hi) ^ (l15 & 7)) << 3)];
        oacc[db] = MFMA16(pf, vf, oacc[db]);
      }
    }
    __builtin_amdgcn_s_setprio(0);

    __syncthreads();   // (c) all waves done reading v_lds

    // stage V(kt+1); exposed per block, hidden by 6-way block TLP on the CU
    if (kt + 1 < NT) {
      int kb = (kt + 1) * 64;
#pragma unroll
      for (int i = 0; i < 2; ++i) {
        int row = i * 32 + st_r0;
        int sc = st_c ^ (row & 7);
        gload16(vh + (size_t)row * VTS_ + kb + sc * 8,
                (char*)&v_lds[0] + (i * 2048 + t * 8) * 2);
      }
    }
  }

#pragma unroll
  for (int r = 0; r < 4; ++r) {
    float ps = lrun[r];
    ps += __shfl_xor(ps, 1);
    ps += __shfl_xor(ps, 2);
    ps += __shfl_xor(ps, 4);
    ps += __shfl_xor(ps, 8);
    int qrow = qt * 64 + w * 16 + hi * 4 + r;
    if (qrow < S_) {
      float inv = 1.0f / ps;
#pragma unroll
      for (int db = 0; db < 4; ++db)
        cx[hoff + (size_t)qrow * D_ + db * 16 + l15] = (bf16)(oacc[db][r] * inv);
    }
  }
}

// ---------------- launch ----------------
extern "C" void kernel_launch(void* const* d_in, const int* in_sizes, int n_in,
                              void* d_out, int out_size, void* d_ws, size_t ws_size,
                              hipStream_t stream) {
  const float* x   = (const float*)d_in[0];
  const float* Wq  = (const float*)d_in[1];
  const float* Wk  = (const float*)d_in[2];
  const float* Wv  = (const float*)d_in[3];
  const float* Wo  = (const float*)d_in[4];
  const float* W1  = (const float*)d_in[5];
  const float* b1  = (const float*)d_in[6];
  const float* W2  = (const float*)d_in[7];
  const float* b2  = (const float*)d_in[8];
  const float* g1  = (const float*)d_in[9];
  const float* be1 = (const float*)d_in[10];
  const float* g2  = (const float*)d_in[11];
  const float* be2 = (const float*)d_in[12];
  float* out = (float*)d_out;

  char* ws = (char*)d_ws;
  bf16* h_b   = (bf16*)(ws + H_OFF);
  bf16* wq_b  = (bf16*)(ws + WQ_OFF);
  bf16* wk_b  = (bf16*)(ws + WK_OFF);
  bf16* wv_b  = (bf16*)(ws + WV_OFF);
  bf16* wo_b  = (bf16*)(ws + WO_OFF);
  bf16* w1_b  = (bf16*)(ws + W1_OFF);
  bf16* w2_b  = (bf16*)(ws + W2_OFF);
  bf16* q_b   = (bf16*)(ws + Q_OFF);
  bf16* k_b   = (bf16*)(ws + K_OFF);
  bf16* vt_b  = (bf16*)(ws + VT_OFF);
  bf16* act_b = (bf16*)(ws + ACT_OFF);
  bf16* ctx_b = h_b;  // ctx overlays h

  const bool big = ws_size >= NEED_BIG;
  bf16* h2_b = (bf16*)(ws + (big ? H2B_OFF : H2F_OFF));

  // weight converts
  cvt_bf16<<<(D_ * D_) / 1024, 256, 0, stream>>>(Wq, wq_b, D_ * D_);
  cvt_bf16<<<(D_ * D_) / 1024, 256, 0, stream>>>(Wk, wk_b, D_ * D_);
  cvt_bf16<<<(D_ * D_) / 1024, 256, 0, stream>>>(Wv, wv_b, D_ * D_);
  cvt_bf16<<<(D_ * D_) / 1024, 256, 0, stream>>>(Wo, wo_b, D_ * D_);
  cvt_bf16<<<(DFF_ * D_) / 1024, 256, 0, stream>>>(W1, w1_b, DFF_ * D_);
  cvt_bf16<<<(DFF_ * D_) / 1024, 256, 0, stream>>>(W2, w2_b, DFF_ * D_);

  // LN1
  ln_fused<<<M_, 256, 0, stream>>>(x, g1, be1, h_b);

  // fused QKV projection: W = [wq;wk;wv] contiguous, N = 3072; grid (47 x 12) linearized
  gemm256<5><<<47 * 12, 1024, 0, stream>>>(
      h_b, wq_b, M_, 3072, D_, 47, 12, nullptr, nullptr, nullptr, nullptr, q_b, k_b, vt_b);

  // attention (3072 blocks x 256 threads, XCD head-grouped, 6 blocks/CU)
  attn_fwd8<<<3072, 256, 0, stream>>>(q_b, k_b, vt_b, ctx_b);

  // out = x + ctx @ Wo^T   (residual lives in d_out); grid (47 x 4)
  gemm256<3><<<47 * 4, 1024, 0, stream>>>(
      ctx_b, wo_b, M_, D_, D_, 47, 4, nullptr, out, nullptr, x, nullptr, nullptr, nullptr);

  // LN2 reads d_out
  ln_fused<<<M_, 256, 0, stream>>>(out, g2, be2, h2_b);

  if (big) {
    gemm256<2><<<47 * 16, 1024, 0, stream>>>(
        h2_b, w1_b, M_, DFF_, D_, 47, 16, act_b, nullptr, b1, nullptr,
        nullptr, nullptr, nullptr);
    gemm256<3><<<47 * 4, 1024, 0, stream>>>(
        act_b, w2_b, M_, D_, DFF_, 47, 4, nullptr, out, b2, out,
        nullptr, nullptr, nullptr);
  } else {
    for (int c = 0; c < 3; ++c) {
      int r0c = c * 4000;
      int nr = 4000;
      int mt = (nr + 255) / 256;
      gemm256<2><<<mt * 16, 1024, 0, stream>>>(
          h2_b + (size_t)r0c * D_, w1_b, nr, DFF_, D_, mt, 16, act_b, nullptr, b1, nullptr,
          nullptr, nullptr, nullptr);
      gemm_bt<3><<<dim3((nr + 127) / 128, D_ / 128), 256, 0, stream>>>(
          act_b, w2_b, nr, D_, DFF_, nullptr, out + (size_t)r0c * D_, b2,
          out + (size_t)r0c * D_, 0.f);
    }
  }
}

// Round 17
// 634.467 us; speedup vs baseline: 1.0352x; 1.0352x over previous
//
#include <hip/hip_runtime.h>
#include <hip/hip_bf16.h>
#include <cstdint>
#include <cstddef>

// ---------------- problem constants ----------------
#define B_    8
#define S_    1500
#define D_    1024
#define H_    16
#define HD_   64
#define DFF_  4096
#define M_    12000   // B_*S_
#define VTS_  1536    // padded seq stride for V^T

typedef __bf16 bf16;
typedef __attribute__((ext_vector_type(8))) __bf16 bf16x8;
typedef __attribute__((ext_vector_type(4))) float f32x4;

#define MFMA16(a, b, c) __builtin_amdgcn_mfma_f32_16x16x32_bf16((a), (b), (c), 0, 0, 0)

// async global->LDS, 16B per lane (wave-uniform base + lane*16 dest).
static __device__ __forceinline__ void gload16(const void* g, void* l) {
  __builtin_amdgcn_global_load_lds(
      (const __attribute__((address_space(1))) void*)(uintptr_t)g,
      (__attribute__((address_space(3))) void*)(uintptr_t)l, 16, 0, 0);
}

static __device__ __forceinline__ unsigned short f2bu(float v) {
  bf16 h = (bf16)v;
  union { bf16 h; unsigned short u; } c;
  c.h = h;
  return c.u;
}

// ---------------- workspace layout (bytes) ----------------
static constexpr size_t HSZ      = (size_t)M_ * D_ * 2;             // 24,576,000
static constexpr size_t H_OFF    = 0;
static constexpr size_t WQ_OFF   = H_OFF + HSZ;                     // 24,576,000
static constexpr size_t WK_OFF   = WQ_OFF + (size_t)D_ * D_ * 2;
static constexpr size_t WV_OFF   = WK_OFF + (size_t)D_ * D_ * 2;
static constexpr size_t WO_OFF   = WV_OFF + (size_t)D_ * D_ * 2;
static constexpr size_t Q_OFF    = WO_OFF + (size_t)D_ * D_ * 2;    // 32,964,608
static constexpr size_t K_OFF    = Q_OFF + HSZ;                     // 57,540,608
static constexpr size_t VT_OFF   = K_OFF + HSZ;                     // 82,116,608
static constexpr size_t W1_OFF   = VT_OFF + (size_t)128 * 64 * VTS_ * 2;  // 107,282,432
static constexpr size_t W2_OFF   = W1_OFF + (size_t)DFF_ * D_ * 2;  // 115,671,040
static constexpr size_t WS_BASE  = W2_OFF + (size_t)DFF_ * D_ * 2;  // 124,059,648
static constexpr size_t H2B_OFF  = WS_BASE;                         // big path h2
static constexpr size_t NEED_BIG = WS_BASE + HSZ;                   // 148,635,648
static constexpr size_t H2F_OFF  = VT_OFF;                          // fallback h2
static constexpr size_t ACT_OFF  = 0;                               // both paths

// ---------------- fused fp32 -> bf16 convert (all 6 weights, one dispatch) ----------------
// block ranges (1024 elems each): wq/wk/wv/wo = 1024 blocks each (D*D = 1,048,576 elems);
// w1/w2 = 4096 blocks each (DFF*D = 4,194,304 elems). Grid total = 12,288.
__launch_bounds__(256)
__global__ void cvt_all(const float* __restrict__ Wq, const float* __restrict__ Wk,
                        const float* __restrict__ Wv, const float* __restrict__ Wo,
                        const float* __restrict__ W1, const float* __restrict__ W2,
                        bf16* wq, bf16* wk, bf16* wv, bf16* wo, bf16* w1, bf16* w2) {
  const int b = blockIdx.x;
  const float* src;
  bf16* dst;
  int local;
  if      (b < 1024) { src = Wq; dst = wq; local = b; }
  else if (b < 2048) { src = Wk; dst = wk; local = b - 1024; }
  else if (b < 3072) { src = Wv; dst = wv; local = b - 2048; }
  else if (b < 4096) { src = Wo; dst = wo; local = b - 3072; }
  else if (b < 8192) { src = W1; dst = w1; local = b - 4096; }
  else               { src = W2; dst = w2; local = b - 8192; }
  const int i = (local * 256 + threadIdx.x) * 4;
  float4 f = *(const float4*)(src + i);
  ushort4 pk;
  pk.x = f2bu(f.x); pk.y = f2bu(f.y); pk.z = f2bu(f.z); pk.w = f2bu(f.w);
  *reinterpret_cast<ushort4*>((unsigned short*)dst + i) = pk;
}

// ---------------- fused LayerNorm (fp32 in, bf16 out), one block per row ----------------
__launch_bounds__(256)
__global__ void ln_fused(const float* __restrict__ x, const float* __restrict__ g,
                         const float* __restrict__ bb, bf16* __restrict__ out) {
  const int row = blockIdx.x;
  const int t = threadIdx.x;
  const float4 xv = *(const float4*)(x + (size_t)row * D_ + t * 4);
  float s  = xv.x + xv.y + xv.z + xv.w;
  float s2 = xv.x * xv.x + xv.y * xv.y + xv.z * xv.z + xv.w * xv.w;
#pragma unroll
  for (int m = 32; m >= 1; m >>= 1) {
    s  += __shfl_xor(s, m);
    s2 += __shfl_xor(s2, m);
  }
  __shared__ float red[8];
  const int w = t >> 6;
  if ((t & 63) == 0) { red[w] = s; red[4 + w] = s2; }
  __syncthreads();
  s  = red[0] + red[1] + red[2] + red[3];
  s2 = red[4] + red[5] + red[6] + red[7];
  const float mu  = s * (1.0f / D_);
  const float var = s2 * (1.0f / D_) - mu * mu;
  const float rs  = rsqrtf(var + 1e-5f);
  const float4 gv = *(const float4*)(g + t * 4);
  const float4 bv = *(const float4*)(bb + t * 4);
  bf16* o = out + (size_t)row * D_ + t * 4;
  o[0] = (bf16)((xv.x - mu) * rs * gv.x + bv.x);
  o[1] = (bf16)((xv.y - mu) * rs * gv.y + bv.y);
  o[2] = (bf16)((xv.z - mu) * rs * gv.z + bv.z);
  o[3] = (bf16)((xv.w - mu) * rs * gv.w + bv.w);
}

// =====================================================================================
// gemm256 v6 (r14 winner): 16 waves, 64x64/wave, BK=64, 2 LDS buffers, XCD-chunk swizzle.
// EPI: 2 = bias + exact GELU -> bf16; 3 = (+bias) + resid -> fp32 (resid may alias outF);
//      5 = fused QKV epilogue (Q pre-scaled by 0.125*log2e for exp2-domain softmax)
// =====================================================================================
template <int EPI>
__launch_bounds__(1024, 4)
__global__ void gemm256(const bf16* __restrict__ A, const bf16* __restrict__ Bw,
                        int M, int N, int K, int nbx, int nby,
                        bf16* __restrict__ outB, float* outF,
                        const float* __restrict__ bias, const float* resid,
                        bf16* __restrict__ outQ, bf16* __restrict__ outK2,
                        bf16* __restrict__ outV) {
  __shared__ bf16 a_lds[2][256 * 64];
  __shared__ bf16 b_lds[2][256 * 64];

  // bijective XCD-chunk remap (m204)
  const int nwg = nbx * nby;
  const int lid = blockIdx.x;
  const int xcd = lid & 7;
  const int q8 = nwg >> 3, r8 = nwg & 7;
  const int wgid = (xcd < r8 ? xcd * (q8 + 1) : r8 * (q8 + 1) + (xcd - r8) * q8) + (lid >> 3);
  const int bx = wgid / nby;
  const int by = wgid - bx * nby;

  const int t = threadIdx.x;
  const int lane = t & 63, wid = t >> 6;
  const int wm = wid >> 2, wn = wid & 3;
  const int l15 = lane & 15, hi = lane >> 4;
  const int l7 = l15 & 7;
  const int mrow0 = bx * 256;
  const int ncol0 = by * 256;

  const int rl = t >> 3;
  const int sc8 = ((t & 7) ^ (rl & 7)) << 3;
  unsigned offA[2], offB[2];
#pragma unroll
  for (int j = 0; j < 2; ++j) {
    int gr = mrow0 + j * 128 + rl; gr = gr < M ? gr : M - 1;
    offA[j] = (unsigned)gr * (unsigned)K + (unsigned)sc8;
    offB[j] = (unsigned)(ncol0 + j * 128 + rl) * (unsigned)K + (unsigned)sc8;
  }

  f32x4 acc[4][4] = {};

  const int NT = K >> 6;

  {
    char* ad = (char*)&a_lds[0][0];
    char* bd = (char*)&b_lds[0][0];
    gload16(A + offA[0], ad + t * 16);
    gload16(A + offA[1], ad + 16384 + t * 16);
    gload16(Bw + offB[0], bd + t * 16);
    gload16(Bw + offB[1], bd + 16384 + t * 16);
  }
  __syncthreads();

  int buf = 0;
  for (int tt = 0; tt < NT; ++tt) {
    if (tt + 1 < NT) {
      const unsigned k1 = (unsigned)(tt + 1) << 6;
      char* ad = (char*)&a_lds[buf ^ 1][0];
      char* bd = (char*)&b_lds[buf ^ 1][0];
      gload16(A + offA[0] + k1, ad + t * 16);
      gload16(A + offA[1] + k1, ad + 16384 + t * 16);
      gload16(Bw + offB[0] + k1, bd + t * 16);
      gload16(Bw + offB[1] + k1, bd + 16384 + t * 16);
    }

    const bf16* al = &a_lds[buf][0];
    const bf16* bl = &b_lds[buf][0];
#pragma unroll
    for (int kk = 0; kk < 2; ++kk) {
      bf16x8 af_[4], bf_[4];
      const int cc = ((kk * 4 + hi) ^ l7) << 3;
#pragma unroll
      for (int m = 0; m < 4; ++m)
        af_[m] = *(const bf16x8*)&al[(wm * 64 + m * 16 + l15) * 64 + cc];
#pragma unroll
      for (int n = 0; n < 4; ++n)
        bf_[n] = *(const bf16x8*)&bl[(wn * 64 + n * 16 + l15) * 64 + cc];
      __builtin_amdgcn_s_setprio(1);
#pragma unroll
      for (int m = 0; m < 4; ++m)
#pragma unroll
        for (int n = 0; n < 4; ++n)
          acc[m][n] = MFMA16(af_[m], bf_[n], acc[m][n]);
      __builtin_amdgcn_s_setprio(0);
    }

    __syncthreads();
    buf ^= 1;
  }

  const int r0 = hi * 4;

  if constexpr (EPI == 5) {
    const int mm = by >> 2;
    const int nloc0 = (by & 3) * 256;
    if (mm == 2) {
#pragma unroll
      for (int m = 0; m < 4; ++m) {
        int row0 = mrow0 + wm * 64 + m * 16 + r0;
        if (row0 < M) {
          int bb2 = row0 / 1500;
          int s = row0 - bb2 * 1500;
#pragma unroll
          for (int n = 0; n < 4; ++n) {
            int f = nloc0 + wn * 64 + n * 16 + l15;
            size_t a = ((size_t)(bb2 * 16 + (f >> 6)) * 64 + (f & 63)) * VTS_ + s;
            ushort4 pk;
            pk.x = f2bu(acc[m][n][0]);
            pk.y = f2bu(acc[m][n][1]);
            pk.z = f2bu(acc[m][n][2]);
            pk.w = f2bu(acc[m][n][3]);
            *reinterpret_cast<ushort4*>((unsigned short*)outV + a) = pk;
          }
        }
      }
    } else {
      bf16* dst = (mm == 0) ? outQ : outK2;
      const float sc = (mm == 0) ? 0.18033688011112042f : 1.0f;
#pragma unroll
      for (int m = 0; m < 4; ++m) {
#pragma unroll
        for (int n = 0; n < 4; ++n) {
          int col = nloc0 + wn * 64 + n * 16 + l15;
#pragma unroll
          for (int r = 0; r < 4; ++r) {
            int row = mrow0 + wm * 64 + m * 16 + r0 + r;
            if (row < M) dst[(size_t)row * D_ + col] = (bf16)(acc[m][n][r] * sc);
          }
        }
      }
    }
    return;
  }

#pragma unroll
  for (int m = 0; m < 4; ++m) {
#pragma unroll
    for (int n = 0; n < 4; ++n) {
      int col = ncol0 + wn * 64 + n * 16 + l15;
#pragma unroll
      for (int r = 0; r < 4; ++r) {
        int row = mrow0 + wm * 64 + m * 16 + r0 + r;
        if (row < M) {
          float v = acc[m][n][r];
          if constexpr (EPI == 2) {
            float xg = v + bias[col];
            v = 0.5f * xg * (1.0f + erff(xg * 0.70710678118654752f));
            outB[(size_t)row * N + col] = (bf16)v;
          }
          if constexpr (EPI == 3) {
            v += resid[(size_t)row * N + col];
            if (bias) v += bias[col];
            outF[(size_t)row * N + col] = v;
          }
        }
      }
    }
  }
}

// ---------------- legacy 128x128 GEMM (fallback FFN2 only) ----------------
template <int EPI>
__launch_bounds__(256)
__global__ void gemm_bt(const bf16* __restrict__ A, const bf16* __restrict__ Bw,
                        int M, int N, int K,
                        bf16* __restrict__ outB, float* outF,
                        const float* __restrict__ bias, const float* resid,
                        float scale) {
  __shared__ bf16 a_lds[128 * 64];
  __shared__ bf16 b_lds[128 * 64];
  const int t = threadIdx.x;
  const int lane = t & 63, wid = t >> 6;
  const int wr = wid >> 1, wc = wid & 1;
  const int mrow0 = blockIdx.x * 128;
  const int ncol0 = blockIdx.y * 128;
  const int l15 = lane & 15;
  const int khi = (lane >> 4) << 3;

  f32x4 acc[4][4] = {};

  for (int k0 = 0; k0 < K; k0 += 64) {
#pragma unroll
    for (int i = 0; i < 4; ++i) {
      int idx = i * 2048 + t * 8;
      int row = idx >> 6, col = idx & 63;
      int gr = mrow0 + row;
      gr = gr < M ? gr : M - 1;
      gload16(A + (size_t)gr * K + (k0 + col), (char*)a_lds + idx * 2);
    }
#pragma unroll
    for (int i = 0; i < 4; ++i) {
      int idx = i * 2048 + t * 8;
      int row = idx >> 6, col = idx & 63;
      gload16(Bw + (size_t)(ncol0 + row) * K + (k0 + col), (char*)b_lds + idx * 2);
    }
    __syncthreads();
#pragma unroll
    for (int kk = 0; kk < 2; ++kk) {
      bf16x8 af[4], bfv[4];
#pragma unroll
      for (int m = 0; m < 4; ++m)
        af[m] = *(const bf16x8*)&a_lds[(wr * 64 + m * 16 + l15) * 64 + kk * 32 + khi];
#pragma unroll
      for (int n = 0; n < 4; ++n)
        bfv[n] = *(const bf16x8*)&b_lds[(wc * 64 + n * 16 + l15) * 64 + kk * 32 + khi];
#pragma unroll
      for (int m = 0; m < 4; ++m)
#pragma unroll
        for (int n = 0; n < 4; ++n)
          acc[m][n] = MFMA16(af[m], bfv[n], acc[m][n]);
    }
    __syncthreads();
  }

  const int r0 = (lane >> 4) << 2;
#pragma unroll
  for (int m = 0; m < 4; ++m) {
#pragma unroll
    for (int n = 0; n < 4; ++n) {
      int col = ncol0 + wc * 64 + n * 16 + l15;
#pragma unroll
      for (int r = 0; r < 4; ++r) {
        int row = mrow0 + wr * 64 + m * 16 + r0 + r;
        if (row < M) {
          float v = acc[m][n][r];
          if constexpr (EPI == 2) {
            float xg = v + bias[col];
            v = 0.5f * xg * (1.0f + erff(xg * 0.70710678118654752f));
          }
          if constexpr (EPI == 3) {
            v += resid[(size_t)row * N + col];
            if (bias) v += bias[col];
            outF[(size_t)row * N + col] = v;
          } else {
            outB[(size_t)row * N + col] = (bf16)v;
          }
        }
      }
    }
  }
}

// ---------------- flash attention fwd v6 (proven 190 us, verbatim) ----------------
__launch_bounds__(256, 4)
__global__ void attn_fwd6(const bf16* __restrict__ q, const bf16* __restrict__ kg,
                          const bf16* __restrict__ vt, bf16* __restrict__ cx) {
  __shared__ bf16 k_lds[2][64 * 64];
  __shared__ bf16 v_lds[2][64 * 64];
  __shared__ bf16 p_lds[4][16 * 64];   // stride 64, XOR chunk swizzle (0 conflicts)

  const int t = threadIdx.x;
  const int lane = t & 63, w = t >> 6;
  const int L = blockIdx.x;
  const int wu = (L & 7) * 384 + (L >> 3);   // XCD head-grouping
  const int bh = wu / 24;
  const int qt = wu - bh * 24;
  const int l15 = lane & 15;
  const int hi = lane >> 4;
  const int khi = hi << 3;

  const size_t hoff = ((size_t)(bh >> 4) * S_) * D_ + (size_t)(bh & 15) * HD_;
  const bf16* qh = q + hoff;
  const bf16* kh = kg + hoff;
  const bf16* vh = vt + (size_t)bh * (64 * VTS_);

  const int st_r0 = t >> 3;
  const int st_c  = t & 7;

  int qr = qt * 64 + w * 16 + l15;
  int qrc = qr < S_ ? qr : S_ - 1;
  const bf16x8 qf0 = *(const bf16x8*)(qh + (size_t)qrc * D_ + khi);
  const bf16x8 qf1 = *(const bf16x8*)(qh + (size_t)qrc * D_ + 32 + khi);

  f32x4 oacc[4] = {};
  float mrun[4], lrun[4];
#pragma unroll
  for (int r = 0; r < 4; ++r) { mrun[r] = -1e30f; lrun[r] = 0.f; }

  bf16* pw = &p_lds[w][0];
  const int NT = (S_ + 63) / 64;  // 24
  const float THR = 11.5415605f;  // 8 nats in log2 domain

#pragma unroll
  for (int i = 0; i < 2; ++i) {
    int row = i * 32 + st_r0;
    int sc = st_c ^ (row & 7);
    int key = row < S_ ? row : S_ - 1;
    gload16(kh + (size_t)key * D_ + sc * 8, (char*)&k_lds[0][0] + (i * 2048 + t * 8) * 2);
    gload16(vh + (size_t)row * VTS_ + sc * 8, (char*)&v_lds[0][0] + (i * 2048 + t * 8) * 2);
  }
  __syncthreads();

  int buf = 0;
  for (int kt = 0; kt < NT; ++kt) {
    if (kt + 1 < NT) {
      int kb = (kt + 1) * 64;
#pragma unroll
      for (int i = 0; i < 2; ++i) {
        int row = i * 32 + st_r0;
        int sc = st_c ^ (row & 7);
        int key = kb + row;
        key = key < S_ ? key : S_ - 1;
        gload16(kh + (size_t)key * D_ + sc * 8,
                (char*)&k_lds[buf ^ 1][0] + (i * 2048 + t * 8) * 2);
        gload16(vh + (size_t)row * VTS_ + kb + sc * 8,
                (char*)&v_lds[buf ^ 1][0] + (i * 2048 + t * 8) * 2);
      }
    }

    float pv[4][4];
    __builtin_amdgcn_s_setprio(1);
#pragma unroll
    for (int nb = 0; nb < 4; ++nb) {
      int krow = nb * 16 + l15;
      f32x4 z = {};
      z = MFMA16(qf0, *(const bf16x8*)&k_lds[buf][krow * 64 + ((hi ^ (l15 & 7)) << 3)], z);
      z = MFMA16(qf1, *(const bf16x8*)&k_lds[buf][krow * 64 + (((4 + hi) ^ (l15 & 7)) << 3)], z);
#pragma unroll
      for (int r = 0; r < 4; ++r) pv[nb][r] = z[r];
    }
    __builtin_amdgcn_s_setprio(0);

    if (kt == NT - 1) {
#pragma unroll
      for (int nb = 0; nb < 4; ++nb) {
        bool cvld = (kt * 64 + nb * 16 + l15) < S_;
#pragma unroll
        for (int r = 0; r < 4; ++r) pv[nb][r] = cvld ? pv[nb][r] : -1e30f;
      }
    }

    float lmax[4];
    bool ok = true;
#pragma unroll
    for (int r = 0; r < 4; ++r) {
      lmax[r] = fmaxf(fmaxf(pv[0][r], pv[1][r]), fmaxf(pv[2][r], pv[3][r]));
      ok = ok && (lmax[r] <= mrun[r] + THR);
    }
    if (!__all(ok)) {
#pragma unroll
      for (int r = 0; r < 4; ++r) {
        float mx = lmax[r];
        mx = fmaxf(mx, __shfl_xor(mx, 1));
        mx = fmaxf(mx, __shfl_xor(mx, 2));
        mx = fmaxf(mx, __shfl_xor(mx, 4));
        mx = fmaxf(mx, __shfl_xor(mx, 8));
        float mnew = fmaxf(mrun[r], mx);
        float corr = exp2f(mrun[r] - mnew);
        lrun[r] *= corr;
        mrun[r] = mnew;
#pragma unroll
        for (int db = 0; db < 4; ++db) oacc[db][r] *= corr;
      }
    }

#pragma unroll
    for (int r = 0; r < 4; ++r) {
      float p0 = exp2f(pv[0][r] - mrun[r]);
      float p1 = exp2f(pv[1][r] - mrun[r]);
      float p2 = exp2f(pv[2][r] - mrun[r]);
      float p3 = exp2f(pv[3][r] - mrun[r]);
      pv[0][r] = p0; pv[1][r] = p1; pv[2][r] = p2; pv[3][r] = p3;
      lrun[r] += (p0 + p1) + (p2 + p3);
    }

#pragma unroll
    for (int nb = 0; nb < 4; ++nb) {
#pragma unroll
      for (int r = 0; r < 4; ++r) {
        int prow = hi * 4 + r;
        int pcol = (nb * 16 + l15) ^ ((prow & 7) << 3);
        pw[prow * 64 + pcol] = (bf16)pv[nb][r];
      }
    }

    __builtin_amdgcn_s_setprio(1);
#pragma unroll
    for (int kk = 0; kk < 2; ++kk) {
      bf16x8 pf = *(const bf16x8*)&pw[l15 * 64 + (((kk * 4 + hi) ^ (l15 & 7)) << 3)];
#pragma unroll
      for (int db = 0; db < 4; ++db) {
        int vrow = db * 16 + l15;
        bf16x8 vf = *(const bf16x8*)&v_lds[buf][vrow * 64 + (((kk * 4 + hi) ^ (l15 & 7)) << 3)];
        oacc[db] = MFMA16(pf, vf, oacc[db]);
      }
    }
    __builtin_amdgcn_s_setprio(0);

    __syncthreads();
    buf ^= 1;
  }

#pragma unroll
  for (int r = 0; r < 4; ++r) {
    float ps = lrun[r];
    ps += __shfl_xor(ps, 1);
    ps += __shfl_xor(ps, 2);
    ps += __shfl_xor(ps, 4);
    ps += __shfl_xor(ps, 8);
    int qrow = qt * 64 + w * 16 + hi * 4 + r;
    if (qrow < S_) {
      float inv = 1.0f / ps;
#pragma unroll
      for (int db = 0; db < 4; ++db)
        cx[hoff + (size_t)qrow * D_ + db * 16 + l15] = (bf16)(oacc[db][r] * inv);
    }
  }
}

// ---------------- launch ----------------
extern "C" void kernel_launch(void* const* d_in, const int* in_sizes, int n_in,
                              void* d_out, int out_size, void* d_ws, size_t ws_size,
                              hipStream_t stream) {
  const float* x   = (const float*)d_in[0];
  const float* Wq  = (const float*)d_in[1];
  const float* Wk  = (const float*)d_in[2];
  const float* Wv  = (const float*)d_in[3];
  const float* Wo  = (const float*)d_in[4];
  const float* W1  = (const float*)d_in[5];
  const float* b1  = (const float*)d_in[6];
  const float* W2  = (const float*)d_in[7];
  const float* b2  = (const float*)d_in[8];
  const float* g1  = (const float*)d_in[9];
  const float* be1 = (const float*)d_in[10];
  const float* g2  = (const float*)d_in[11];
  const float* be2 = (const float*)d_in[12];
  float* out = (float*)d_out;

  char* ws = (char*)d_ws;
  bf16* h_b   = (bf16*)(ws + H_OFF);
  bf16* wq_b  = (bf16*)(ws + WQ_OFF);
  bf16* wk_b  = (bf16*)(ws + WK_OFF);
  bf16* wv_b  = (bf16*)(ws + WV_OFF);
  bf16* wo_b  = (bf16*)(ws + WO_OFF);
  bf16* w1_b  = (bf16*)(ws + W1_OFF);
  bf16* w2_b  = (bf16*)(ws + W2_OFF);
  bf16* q_b   = (bf16*)(ws + Q_OFF);
  bf16* k_b   = (bf16*)(ws + K_OFF);
  bf16* vt_b  = (bf16*)(ws + VT_OFF);
  bf16* act_b = (bf16*)(ws + ACT_OFF);
  bf16* ctx_b = h_b;  // ctx overlays h

  const bool big = ws_size >= NEED_BIG;
  bf16* h2_b = (bf16*)(ws + (big ? H2B_OFF : H2F_OFF));

  // all 6 weight converts in ONE dispatch (12,288 blocks; ranges verified vs sizes)
  cvt_all<<<12288, 256, 0, stream>>>(Wq, Wk, Wv, Wo, W1, W2,
                                     wq_b, wk_b, wv_b, wo_b, w1_b, w2_b);

  // LN1
  ln_fused<<<M_, 256, 0, stream>>>(x, g1, be1, h_b);

  // fused QKV projection: W = [wq;wk;wv] contiguous, N = 3072; grid (47 x 12) linearized
  gemm256<5><<<47 * 12, 1024, 0, stream>>>(
      h_b, wq_b, M_, 3072, D_, 47, 12, nullptr, nullptr, nullptr, nullptr, q_b, k_b, vt_b);

  // attention (3072 blocks x 256 threads, XCD head-grouped)
  attn_fwd6<<<3072, 256, 0, stream>>>(q_b, k_b, vt_b, ctx_b);

  // out = x + ctx @ Wo^T   (residual lives in d_out); grid (47 x 4)
  gemm256<3><<<47 * 4, 1024, 0, stream>>>(
      ctx_b, wo_b, M_, D_, D_, 47, 4, nullptr, out, nullptr, x, nullptr, nullptr, nullptr);

  // LN2 reads d_out
  ln_fused<<<M_, 256, 0, stream>>>(out, g2, be2, h2_b);

  if (big) {
    gemm256<2><<<47 * 16, 1024, 0, stream>>>(
        h2_b, w1_b, M_, DFF_, D_, 47, 16, act_b, nullptr, b1, nullptr,
        nullptr, nullptr, nullptr);
    gemm256<3><<<47 * 4, 1024, 0, stream>>>(
        act_b, w2_b, M_, D_, DFF_, 47, 4, nullptr, out, b2, out,
        nullptr, nullptr, nullptr);
  } else {
    for (int c = 0; c < 3; ++c) {
      int r0c = c * 4000;
      int nr = 4000;
      int mt = (nr + 255) / 256;
      gemm256<2><<<mt * 16, 1024, 0, stream>>>(
          h2_b + (size_t)r0c * D_, w1_b, nr, DFF_, D_, mt, 16, act_b, nullptr, b1, nullptr,
          nullptr, nullptr, nullptr);
      gemm_bt<3><<<dim3((nr + 127) / 128, D_ / 128), 256, 0, stream>>>(
          act_b, w2_b, nr, D_, DFF_, nullptr, out + (size_t)r0c * D_, b2,
          out + (size_t)r0c * D_, 0.f);
    }
  }
}